// Round 3
// baseline (3444.704 us; speedup 1.0000x reference)
//
#include <hip/hip_runtime.h>
#include <cstdint>
#include <cstddef>

#define B_ 64
#define S_ 512
#define D_ 1024
#define H_ 1024
#define G_ 4096       // 4*H
#define NBLK 256      // 4 batch-groups x 64 col-groups

typedef short short8 __attribute__((ext_vector_type(8)));
typedef float floatx4 __attribute__((ext_vector_type(4)));

__device__ __forceinline__ unsigned short bf16_rne(float f) {
  union { float f; unsigned u; } v; v.f = f;
  return (unsigned short)((v.u + 0x7FFFu + ((v.u >> 16) & 1u)) >> 16);
}
__device__ __forceinline__ float sigf(float x) { return 1.0f / (1.0f + __expf(-x)); }
__device__ __forceinline__ float tanhf_fast(float x) {
  float e = __expf(2.0f * x);
  return 1.0f - 2.0f / (e + 1.0f);   // safe at +-inf (no NaN)
}

// agent-scope coherent store (proven publish path from round-0 kernel)
__device__ __forceinline__ void astore64(void* p, uint64_t v) {
  __hip_atomic_store((unsigned long long*)p, (unsigned long long)v,
                     __ATOMIC_RELAXED, __HIP_MEMORY_SCOPE_AGENT);
}
// 4x16B coherent loads (L1/L2 bypass -> coherence point) + single wait
__device__ __forceinline__ void cpoll64(uint4* a, uint4* b, uint4* c, uint4* d, const void* p) {
  asm volatile("global_load_dwordx4 %0, %4, off sc0 sc1\n\t"
               "global_load_dwordx4 %1, %4, off offset:16 sc0 sc1\n\t"
               "global_load_dwordx4 %2, %4, off offset:32 sc0 sc1\n\t"
               "global_load_dwordx4 %3, %4, off offset:48 sc0 sc1\n\t"
               "s_waitcnt vmcnt(0)"
               : "=&v"(*a), "=&v"(*b), "=&v"(*c), "=&v"(*d)
               : "v"(p) : "memory");
}

// raw barrier (no vmcnt drain) for S4 only: LDS ordering via lgkmcnt; the
// hout reuse hazard is additionally covered by S1's full __syncthreads.
#define BARRIER_LGKM() do {                                   \
    asm volatile("s_waitcnt lgkmcnt(0)" ::: "memory");        \
    __builtin_amdgcn_s_barrier();                             \
    asm volatile("" ::: "memory");                            \
  } while (0)

// ---------------- prep kernels ----------------
__global__ void f32_to_bf16_k(const float* __restrict__ s, unsigned short* __restrict__ d, int n) {
  int i = (blockIdx.x * 256 + threadIdx.x) * 4;
  if (i < n) {
    float4 v = *(const float4*)(s + i);
    ushort4 o;
    o.x = bf16_rne(v.x); o.y = bf16_rne(v.y); o.z = bf16_rne(v.z); o.w = bf16_rne(v.w);
    *(ushort4*)(d + i) = o;
  }
}

__global__ void bsum_k(const float* __restrict__ bi, const float* __restrict__ bh, float* __restrict__ o) {
  int i = blockIdx.x * 256 + threadIdx.x;
  if (i < G_) o[i] = bi[i] + bh[i];
}

// h(0) as tagged u32: (bf16<<16) | tag0
__global__ void hinit_k(const float* __restrict__ h0, unsigned* __restrict__ hb32) {
  int i = blockIdx.x * 256 + threadIdx.x;   // 0..65535
  if (i < B_ * H_) hb32[i] = ((unsigned)bf16_rne(h0[i & (H_ - 1)])) << 16;
}

// ---------------- phase 1: xg = x @ Wi^T + (bi+bh) ----------------
__global__ __launch_bounds__(256, 3) void gemm_xg(
    const unsigned short* __restrict__ xa,   // [32768][1024] bf16 (token-major: b*512+s)
    const unsigned short* __restrict__ wb,   // [4096][1024] bf16
    const float* __restrict__ bsum,          // [4096]
    void* __restrict__ xgv, int xg16)        // out: [512][64][4096]
{
  __shared__ unsigned short As[128 * 72];
  __shared__ unsigned short Bs[128 * 72];
  const int tid = threadIdx.x, ln = tid & 63, wv = tid >> 6;
  const int q = ln >> 4, lr = ln & 15;
  const int bid = blockIdx.x;
  const int nt = bid & 31, mt = bid >> 5;
  const int m0 = mt << 7, n0 = nt << 7;
  const int wm = (wv & 1) << 6, wn = (wv >> 1) << 6;
  floatx4 acc[4][4] = {};

  for (int kk = 0; kk < 1024; kk += 64) {
    __syncthreads();
#pragma unroll
    for (int i = 0; i < 4; i++) {
      int f = i * 256 + tid;
      int row = f >> 3, c8 = (f & 7) << 3;
      short8 va = *(const short8*)(xa + (size_t)(m0 + row) * 1024 + kk + c8);
      short8 vb = *(const short8*)(wb + (size_t)(n0 + row) * 1024 + kk + c8);
      *(short8*)(As + row * 72 + c8) = va;
      *(short8*)(Bs + row * 72 + c8) = vb;
    }
    __syncthreads();
#pragma unroll
    for (int ks = 0; ks < 2; ks++) {
      short8 af[4], bf[4];
#pragma unroll
      for (int mi = 0; mi < 4; mi++)
        af[mi] = *(const short8*)(As + (wm + mi * 16 + lr) * 72 + ks * 32 + q * 8);
#pragma unroll
      for (int ni = 0; ni < 4; ni++)
        bf[ni] = *(const short8*)(Bs + (wn + ni * 16 + lr) * 72 + ks * 32 + q * 8);
#pragma unroll
      for (int mi = 0; mi < 4; mi++)
#pragma unroll
        for (int ni = 0; ni < 4; ni++)
          acc[mi][ni] = __builtin_amdgcn_mfma_f32_16x16x32_bf16(af[mi], bf[ni], acc[mi][ni], 0, 0, 0);
    }
  }
  const int b = m0 >> 9, s0 = m0 & 511;
#pragma unroll
  for (int mi = 0; mi < 4; mi++) {
#pragma unroll
    for (int r = 0; r < 4; r++) {
      int mrow = wm + mi * 16 + q * 4 + r;
      size_t base = (size_t)(s0 + mrow) * (B_ * G_) + (size_t)b * G_;
#pragma unroll
      for (int ni = 0; ni < 4; ni++) {
        int n = n0 + wn + ni * 16 + lr;
        float v = acc[mi][ni][r] + bsum[n];
        if (xg16) ((unsigned short*)xgv)[base + n] = bf16_rne(v);
        else      ((float*)xgv)[base + n] = v;
      }
    }
  }
}

// ---------------- phase 2: persistent recurrence, tagged-h sync ----------------
// Round-0 body (phases A..F, S1..S3 = __syncthreads) with the flag machinery
// replaced by self-validating tagged h: publish (bf16<<16)|t+1 fire-and-forget;
// staging polls its own h rows until all tags == t. Buffer reuse is race-free:
// a block publishes t+2 only after observing t+1 from every block of its bg,
// which (via S1..S3) implies all step-t reads completed.
__global__ __launch_bounds__(1024, 1) void lstm_rec(
    const void* __restrict__ xgv, int xg16,  // [512][64][4096] (biases folded in)
    const unsigned short* __restrict__ wh,   // [4096][1024] bf16
    unsigned* __restrict__ hb32,             // [2][64][1024] u32 tagged h
    const float* __restrict__ c0,            // [1024]
    float* __restrict__ out_hid,             // [64][512][1024]
    float* __restrict__ out_h,               // [64][1024]
    float* __restrict__ out_c)               // [64][1024]
{
  __shared__ unsigned short hs[16 * 1032];   // h tile bf16, padded rows
  __shared__ float red[3][4][16][16];        // K-split partials [kt-1][nt][m][n]
  __shared__ unsigned short hout_bf[256];    // 16x16 h tile bf16 (publish)
  __shared__ float hout_f[256];              // 16x16 h tile fp32 (out_hid)

  const int tid = threadIdx.x, ln = tid & 63, wv = tid >> 6;
  const int nt = wv & 3, kt = wv >> 2;
  const int bid = blockIdx.x, bg = bid & 3, cg = bid >> 2;
  const int r0 = bg << 4, j0 = cg << 4;
  const int nloc = ln & 15, q = ln >> 4;
  const int tg = nloc >> 2, u = nloc & 3;
  const int j = j0 + (nt << 2) + u;
  const int gcol = tg * 1024 + j;

  // persistent Wh slice in registers
  short8 bfr[8];
#pragma unroll
  for (int s8 = 0; s8 < 8; s8++)
    bfr[s8] = *(const short8*)(wh + (size_t)gcol * 1024 + kt * 256 + s8 * 32 + q * 8);

  float cst[4];
#pragma unroll
  for (int r = 0; r < 4; r++) cst[r] = c0[j];

  // staging geometry: wave wv stages row wv; each lane 16 u32 cols (64B)
  const int srow = tid >> 6, scc = (tid & 63) << 4;

  for (int t = 0; t < 512; t++) {
    // A: xg prefetch (plain cached loads; drained by phase-B's vmcnt(0),
    // so their HBM latency overlaps the h poll — round-0 arrangement)
    float xv[4] = {0.f, 0.f, 0.f, 0.f};
    if (kt == 0) {
      const size_t xbase = (size_t)t * (B_ * G_) + (size_t)r0 * G_ + gcol;
      if (xg16) {
#pragma unroll
        for (int r = 0; r < 4; r++) {
          unsigned short w = ((const unsigned short*)xgv)[xbase + (size_t)(q * 4 + r) * G_];
          union { unsigned uu; float ff; } cv; cv.uu = ((unsigned)w) << 16; xv[r] = cv.ff;
        }
      } else {
#pragma unroll
        for (int r = 0; r < 4; r++)
          xv[r] = ((const float*)xgv)[xbase + (size_t)(q * 4 + r) * G_];
      }
    }

    // B: self-validating tagged poll of h(t), pack -> LDS
    {
      const unsigned* hp = hb32 + (size_t)(t & 1) * (B_ * H_)
                         + ((size_t)(r0 + srow) << 10) + scc;
      const unsigned tg16 = (unsigned)t & 0xffffu;
      uint4 w0, w1, w2, w3;
      for (;;) {
        cpoll64(&w0, &w1, &w2, &w3, hp);
        unsigned dv = ((w0.x ^ tg16) | (w0.y ^ tg16) | (w0.z ^ tg16) | (w0.w ^ tg16)
                     | (w1.x ^ tg16) | (w1.y ^ tg16) | (w1.z ^ tg16) | (w1.w ^ tg16)
                     | (w2.x ^ tg16) | (w2.y ^ tg16) | (w2.z ^ tg16) | (w2.w ^ tg16)
                     | (w3.x ^ tg16) | (w3.y ^ tg16) | (w3.z ^ tg16) | (w3.w ^ tg16)) & 0xffffu;
        if (dv == 0) break;
        __builtin_amdgcn_s_sleep(2);
      }
      unsigned* hd = (unsigned*)(hs + srow * 1032 + scc);
      hd[0] = (w0.x >> 16) | (w0.y & 0xffff0000u);
      hd[1] = (w0.z >> 16) | (w0.w & 0xffff0000u);
      hd[2] = (w1.x >> 16) | (w1.y & 0xffff0000u);
      hd[3] = (w1.z >> 16) | (w1.w & 0xffff0000u);
      hd[4] = (w2.x >> 16) | (w2.y & 0xffff0000u);
      hd[5] = (w2.z >> 16) | (w2.w & 0xffff0000u);
      hd[6] = (w3.x >> 16) | (w3.y & 0xffff0000u);
      hd[7] = (w3.z >> 16) | (w3.w & 0xffff0000u);
    }
    __syncthreads();   // S1: hs ready

    // C: partial gates over this wave's K chunk
    floatx4 acc = {0.f, 0.f, 0.f, 0.f};
#pragma unroll
    for (int s8 = 0; s8 < 8; s8++) {
      short8 af = *(const short8*)(hs + nloc * 1032 + kt * 256 + s8 * 32 + q * 8);
      acc = __builtin_amdgcn_mfma_f32_16x16x32_bf16(af, bfr[s8], acc, 0, 0, 0);
    }
    if (kt) {
#pragma unroll
      for (int r = 0; r < 4; r++) red[kt - 1][nt][q * 4 + r][nloc] = acc[r];
    }
    __syncthreads();   // S2: red ready

    // D: epilogue (kt==0 waves)
    if (kt == 0) {
      float gv[4];
#pragma unroll
      for (int r = 0; r < 4; r++)
        gv[r] = acc[r] + red[0][nt][q * 4 + r][nloc] + red[1][nt][q * 4 + r][nloc]
              + red[2][nt][q * 4 + r][nloc] + xv[r];
      const int sb = q << 4;
#pragma unroll
      for (int r = 0; r < 4; r++) {
        float vi = __shfl(gv[r], sb + u);
        float vf = __shfl(gv[r], sb + 4 + u);
        float vg = __shfl(gv[r], sb + 8 + u);
        float vo = __shfl(gv[r], sb + 12 + u);
        float i_ = sigf(vi), f_ = sigf(vf), g_ = tanhf_fast(vg), o_ = sigf(vo);
        float cn = f_ * cst[r] + i_ * g_;
        cst[r] = cn;
        float hn = o_ * tanhf_fast(cn);
        if (tg == 0) {
          int m = (q << 2) + r;
          hout_bf[(m << 4) + (nt << 2) + u] = bf16_rne(hn);
          hout_f [(m << 4) + (nt << 2) + u] = hn;
          if (t == 511) {
            int brow = r0 + m;
            out_h[(brow << 10) + j] = hn;
            out_c[(brow << 10) + j] = cn;
          }
        }
      }
    }
    __syncthreads();   // S3: hout ready

    if (wv == 0) {
      if (t < 511) {
        // E: tagged publish, fire-and-forget (no ack, no arrival, no flags).
        // lane ln: row = ln>>2, 4 consecutive cols; two u64 agent stores.
        unsigned* hw32 = hb32 + (size_t)((t + 1) & 1) * (B_ * H_);
        const int row = ln >> 2, c4 = (ln & 3) << 2;
        const uint64_t tag = (unsigned)(t + 1);
        const unsigned short* hb4 = hout_bf + (row << 4) + c4;
        uint64_t w01 = ((((uint64_t)hb4[0] << 16) | tag))
                     | ((((uint64_t)hb4[1] << 16) | tag) << 32);
        uint64_t w23 = ((((uint64_t)hb4[2] << 16) | tag))
                     | ((((uint64_t)hb4[3] << 16) | tag) << 32);
        unsigned* dst = hw32 + ((size_t)(r0 + row) << 10) + j0 + c4;
        astore64(dst, w01);
        astore64(dst + 2, w23);
      }
    } else if (wv == 1) {
      // F: out_hid rows (plain cached stores; drain overlaps next staging)
      int row = ln >> 2, c4 = (ln & 3) << 2;
      float4 fv = *(const float4*)(hout_f + (row << 4) + c4);
      *(float4*)(out_hid + (size_t)(r0 + row) * (S_ * H_) + (size_t)t * H_ + j0 + c4) = fv;
    }
    BARRIER_LGKM();    // S4: raw barrier, NO vmcnt drain (publish stays in flight;
                       // consumers self-validate via tags; S1 next iter re-fences LDS)
  }
}

// ---------------- host ----------------
extern "C" void kernel_launch(void* const* d_in, const int* in_sizes, int n_in,
                              void* d_out, int out_size, void* d_ws, size_t ws_size,
                              hipStream_t stream) {
  const float* x  = (const float*)d_in[0];
  const float* h0 = (const float*)d_in[1];
  const float* c0 = (const float*)d_in[2];
  const float* Wi = (const float*)d_in[3];
  const float* bi = (const float*)d_in[4];
  const float* Wh = (const float*)d_in[5];
  const float* bh = (const float*)d_in[6];

  float* out_hid = (float*)d_out;
  float* out_h = out_hid + (size_t)B_ * S_ * H_;
  float* out_c = out_h + (size_t)B_ * H_;

  uint8_t* ws = (uint8_t*)d_ws;
  const size_t xg_fp32 = (size_t)S_ * B_ * G_ * 4;   // 512 MB
  const size_t xg_bf16 = (size_t)S_ * B_ * G_ * 2;   // 256 MB
  const size_t xbf_b = (size_t)B_ * S_ * D_ * 2;     // 64 MB
  const size_t w_b = (size_t)G_ * D_ * 2;            // 8 MB each
  const size_t hb_b = (size_t)2 * B_ * H_ * 4;       // 512 KB tagged h
  const size_t rest = xbf_b + 2 * w_b + (size_t)G_ * 4 + hb_b + 8192;
  int xg16 = (ws_size >= xg_fp32 + rest) ? 0 : 1;
  size_t xg_bytes = xg16 ? xg_bf16 : xg_fp32;

  size_t off = 0;
  void* xg = (void*)(ws + off);                      off += xg_bytes;
  unsigned short* xbf = (unsigned short*)(ws + off); off += xbf_b;
  unsigned short* wib = (unsigned short*)(ws + off); off += w_b;
  unsigned short* whb = (unsigned short*)(ws + off); off += w_b;
  float* bsum = (float*)(ws + off);                  off += (size_t)G_ * 4;
  unsigned* hb32 = (unsigned*)(ws + off);            off += hb_b;

  // kill stale tags from previous launches/replays (0xFFFF matches no t<512),
  // then write h(0) with tag 0 into buffer 0
  hipMemsetAsync(hb32, 0xFF, hb_b, stream);
  f32_to_bf16_k<<<(B_ * S_ * D_ / 4 + 255) / 256, 256, 0, stream>>>(x, xbf, B_ * S_ * D_);
  f32_to_bf16_k<<<(G_ * D_ / 4 + 255) / 256, 256, 0, stream>>>(Wi, wib, G_ * D_);
  f32_to_bf16_k<<<(G_ * D_ / 4 + 255) / 256, 256, 0, stream>>>(Wh, whb, G_ * D_);
  bsum_k<<<G_ / 256, 256, 0, stream>>>(bi, bh, bsum);
  hinit_k<<<(B_ * H_ + 255) / 256, 256, 0, stream>>>(h0, hb32);

  gemm_xg<<<dim3((S_ * B_ / 128) * (G_ / 128)), 256, 0, stream>>>(xbf, wib, bsum, xg, xg16);

  void* args[] = { (void*)&xg, (void*)&xg16, (void*)&whb, (void*)&hb32, (void*)&c0,
                   (void*)&out_hid, (void*)&out_h, (void*)&out_c };
  hipLaunchCooperativeKernel((void*)lstm_rec, dim3(NBLK), dim3(1024), args, 0, stream);
}

// Round 4
// 3414.093 us; speedup vs baseline: 1.0090x; 1.0090x over previous
//
#include <hip/hip_runtime.h>
#include <cstdint>
#include <cstddef>

#define B_ 64
#define S_ 512
#define D_ 1024
#define H_ 1024
#define G_ 4096       // 4*H
#define NBLK 256      // 4 batch-groups x 64 col-groups

typedef short short8 __attribute__((ext_vector_type(8)));
typedef float floatx4 __attribute__((ext_vector_type(4)));

__device__ __forceinline__ unsigned short bf16_rne(float f) {
  union { float f; unsigned u; } v; v.f = f;
  return (unsigned short)((v.u + 0x7FFFu + ((v.u >> 16) & 1u)) >> 16);
}
__device__ __forceinline__ float sigf(float x) { return 1.0f / (1.0f + __expf(-x)); }
__device__ __forceinline__ float tanhf_fast(float x) {
  float e = __expf(2.0f * x);
  return 1.0f - 2.0f / (e + 1.0f);   // safe at +-inf (no NaN)
}

// agent-scope coherent ops (proven in rounds 0/3)
__device__ __forceinline__ void astore32(unsigned* p, unsigned v) {
  __hip_atomic_store(p, v, __ATOMIC_RELAXED, __HIP_MEMORY_SCOPE_AGENT);
}
__device__ __forceinline__ unsigned aload32(const unsigned* p) {
  return __hip_atomic_load(p, __ATOMIC_RELAXED, __HIP_MEMORY_SCOPE_AGENT);
}
// 4x16B coherent loads (L1/L2 bypass -> coherence point) + single wait
__device__ __forceinline__ void cpoll64(uint4* a, uint4* b, uint4* c, uint4* d, const void* p) {
  asm volatile("global_load_dwordx4 %0, %4, off sc0 sc1\n\t"
               "global_load_dwordx4 %1, %4, off offset:16 sc0 sc1\n\t"
               "global_load_dwordx4 %2, %4, off offset:32 sc0 sc1\n\t"
               "global_load_dwordx4 %3, %4, off offset:48 sc0 sc1\n\t"
               "s_waitcnt vmcnt(0)"
               : "=&v"(*a), "=&v"(*b), "=&v"(*c), "=&v"(*d)
               : "v"(p) : "memory");
}

// raw barrier: lgkmcnt fence only, NO vmcnt drain (keeps xg prefetch +
// fire-and-forget publishes in flight across it)
#define BARRIER_LGKM() do {                                   \
    asm volatile("s_waitcnt lgkmcnt(0)" ::: "memory");        \
    __builtin_amdgcn_s_barrier();                             \
    asm volatile("" ::: "memory");                            \
  } while (0)

// ---------------- prep kernels ----------------
__global__ void f32_to_bf16_k(const float* __restrict__ s, unsigned short* __restrict__ d, int n) {
  int i = (blockIdx.x * 256 + threadIdx.x) * 4;
  if (i < n) {
    float4 v = *(const float4*)(s + i);
    ushort4 o;
    o.x = bf16_rne(v.x); o.y = bf16_rne(v.y); o.z = bf16_rne(v.z); o.w = bf16_rne(v.w);
    *(ushort4*)(d + i) = o;
  }
}

__global__ void bsum_k(const float* __restrict__ bi, const float* __restrict__ bh, float* __restrict__ o) {
  int i = blockIdx.x * 256 + threadIdx.x;
  if (i < G_) o[i] = bi[i] + bh[i];
}

// h(0) as tagged u32: (bf16<<16) | tag0
__global__ void hinit_k(const float* __restrict__ h0, unsigned* __restrict__ hb32) {
  int i = blockIdx.x * 256 + threadIdx.x;   // 0..65535
  if (i < B_ * H_) hb32[i] = ((unsigned)bf16_rne(h0[i & (H_ - 1)])) << 16;
}

// ---------------- phase 1: xg = x @ Wi^T + (bi+bh) ----------------
__global__ __launch_bounds__(256, 3) void gemm_xg(
    const unsigned short* __restrict__ xa,   // [32768][1024] bf16 (token-major: b*512+s)
    const unsigned short* __restrict__ wb,   // [4096][1024] bf16
    const float* __restrict__ bsum,          // [4096]
    void* __restrict__ xgv, int xg16)        // out: [512][64][4096]
{
  __shared__ unsigned short As[128 * 72];
  __shared__ unsigned short Bs[128 * 72];
  const int tid = threadIdx.x, ln = tid & 63, wv = tid >> 6;
  const int q = ln >> 4, lr = ln & 15;
  const int bid = blockIdx.x;
  const int nt = bid & 31, mt = bid >> 5;
  const int m0 = mt << 7, n0 = nt << 7;
  const int wm = (wv & 1) << 6, wn = (wv >> 1) << 6;
  floatx4 acc[4][4] = {};

  for (int kk = 0; kk < 1024; kk += 64) {
    __syncthreads();
#pragma unroll
    for (int i = 0; i < 4; i++) {
      int f = i * 256 + tid;
      int row = f >> 3, c8 = (f & 7) << 3;
      short8 va = *(const short8*)(xa + (size_t)(m0 + row) * 1024 + kk + c8);
      short8 vb = *(const short8*)(wb + (size_t)(n0 + row) * 1024 + kk + c8);
      *(short8*)(As + row * 72 + c8) = va;
      *(short8*)(Bs + row * 72 + c8) = vb;
    }
    __syncthreads();
#pragma unroll
    for (int ks = 0; ks < 2; ks++) {
      short8 af[4], bf[4];
#pragma unroll
      for (int mi = 0; mi < 4; mi++)
        af[mi] = *(const short8*)(As + (wm + mi * 16 + lr) * 72 + ks * 32 + q * 8);
#pragma unroll
      for (int ni = 0; ni < 4; ni++)
        bf[ni] = *(const short8*)(Bs + (wn + ni * 16 + lr) * 72 + ks * 32 + q * 8);
#pragma unroll
      for (int mi = 0; mi < 4; mi++)
#pragma unroll
        for (int ni = 0; ni < 4; ni++)
          acc[mi][ni] = __builtin_amdgcn_mfma_f32_16x16x32_bf16(af[mi], bf[ni], acc[mi][ni], 0, 0, 0);
    }
  }
  const int b = m0 >> 9, s0 = m0 & 511;
#pragma unroll
  for (int mi = 0; mi < 4; mi++) {
#pragma unroll
    for (int r = 0; r < 4; r++) {
      int mrow = wm + mi * 16 + q * 4 + r;
      size_t base = (size_t)(s0 + mrow) * (B_ * G_) + (size_t)b * G_;
#pragma unroll
      for (int ni = 0; ni < 4; ni++) {
        int n = n0 + wn + ni * 16 + lr;
        float v = acc[mi][ni][r] + bsum[n];
        if (xg16) ((unsigned short*)xgv)[base + n] = bf16_rne(v);
        else      ((float*)xgv)[base + n] = v;
      }
    }
  }
}

// ---------------- phase 2: persistent recurrence ----------------
// Sync = compact arrival HINT (64 dwords/bg, wave0 polls 4 lines) +
// self-validating tagged payload ((bf16<<16)|step, verified by consumers).
// No producer ack, no aggregator, no flag cascade. Publish + out_hid move
// directly into the epilogue (no hout LDS handoff, no S3/S4).
// Race-freedom (same proof as r3, which passed): a block publishes t+2 only
// after its step-t+1 verify, which requires all blocks published t+1, which
// (publish sits after S2) implies all their step-t payload reads completed.
// The hint is correctness-irrelevant: stale/early hints only cause extra
// verify iterations, never wrong data.
__global__ __launch_bounds__(1024, 1) void lstm_rec(
    const void* __restrict__ xgv, int xg16,  // [512][64][4096] (biases folded in)
    const unsigned short* __restrict__ wh,   // [4096][1024] bf16
    unsigned* __restrict__ hb32,             // [2][64][1024] u32 tagged h
    const float* __restrict__ c0,            // [1024]
    float* __restrict__ out_hid,             // [64][512][1024]
    float* __restrict__ out_h,               // [64][1024]
    float* __restrict__ out_c,               // [64][1024]
    unsigned* __restrict__ arr)              // hint: [4][64]
{
  __shared__ unsigned short hs[16 * 1032];   // h tile bf16, padded rows
  __shared__ float red[3][4][16][16];        // K-split partials [kt-1][nt][m][n]

  const int tid = threadIdx.x, ln = tid & 63, wv = tid >> 6;
  const int nt = wv & 3, kt = wv >> 2;
  const int bid = blockIdx.x, bg = bid & 3, cg = bid >> 2;
  const int r0 = bg << 4, j0 = cg << 4;
  const int nloc = ln & 15, q = ln >> 4;
  const int tg = nloc >> 2, u = nloc & 3;
  const int j = j0 + (nt << 2) + u;
  const int gcol = tg * 1024 + j;

  unsigned* arr_bg = arr + (bg << 6);        // 64 dwords = 4 cache lines

  // persistent Wh slice in registers
  short8 bfr[8];
#pragma unroll
  for (int s8 = 0; s8 < 8; s8++)
    bfr[s8] = *(const short8*)(wh + (size_t)gcol * 1024 + kt * 256 + s8 * 32 + q * 8);

  float cst[4];
#pragma unroll
  for (int r = 0; r < 4; r++) cst[r] = c0[j];

  // staging geometry: wave srow stages row srow; each lane 16 u32 cols (64B)
  const int srow = tid >> 6, scc = (tid & 63) << 4;

  for (int t = 0; t < 512; t++) {
    // A: xg prefetch (plain cached loads; in flight through the hint barrier,
    // drained by the verify loop's vmcnt(0) -> latency fully overlapped)
    float xv[4] = {0.f, 0.f, 0.f, 0.f};
    if (kt == 0) {
      const size_t xbase = (size_t)t * (B_ * G_) + (size_t)r0 * G_ + gcol;
      if (xg16) {
#pragma unroll
        for (int r = 0; r < 4; r++) {
          unsigned short w = ((const unsigned short*)xgv)[xbase + (size_t)(q * 4 + r) * G_];
          union { unsigned uu; float ff; } cv; cv.uu = ((unsigned)w) << 16; xv[r] = cv.ff;
        }
      } else {
#pragma unroll
        for (int r = 0; r < 4; r++)
          xv[r] = ((const float*)xgv)[xbase + (size_t)(q * 4 + r) * G_];
      }
    }

    // B0: arrival hint — wave0 polls 64 compact slots (lane i -> slot i);
    // tiny traffic (4 lines/block/round). Hint only: payload still verified.
    if (wv == 0) {
      const unsigned tgt = (unsigned)t;
      for (;;) {
        unsigned v = aload32(arr_bg + ln);
        if (__all((int)(v >= tgt))) break;
        __builtin_amdgcn_s_sleep(1);
      }
    }
    BARRIER_LGKM();   // release all waves; no vmcnt drain

    // B: payload load + tag verify (expected 1 iteration), pack -> LDS
    {
      const unsigned* hp = hb32 + (size_t)(t & 1) * (B_ * H_)
                         + ((size_t)(r0 + srow) << 10) + scc;
      const unsigned tg16 = (unsigned)t & 0xffffu;
      uint4 w0, w1, w2, w3;
      for (;;) {
        cpoll64(&w0, &w1, &w2, &w3, hp);
        unsigned dv = ((w0.x ^ tg16) | (w0.y ^ tg16) | (w0.z ^ tg16) | (w0.w ^ tg16)
                     | (w1.x ^ tg16) | (w1.y ^ tg16) | (w1.z ^ tg16) | (w1.w ^ tg16)
                     | (w2.x ^ tg16) | (w2.y ^ tg16) | (w2.z ^ tg16) | (w2.w ^ tg16)
                     | (w3.x ^ tg16) | (w3.y ^ tg16) | (w3.z ^ tg16) | (w3.w ^ tg16)) & 0xffffu;
        if (dv == 0) break;
        __builtin_amdgcn_s_sleep(2);
      }
      unsigned* hd = (unsigned*)(hs + srow * 1032 + scc);
      hd[0] = (w0.x >> 16) | (w0.y & 0xffff0000u);
      hd[1] = (w0.z >> 16) | (w0.w & 0xffff0000u);
      hd[2] = (w1.x >> 16) | (w1.y & 0xffff0000u);
      hd[3] = (w1.z >> 16) | (w1.w & 0xffff0000u);
      hd[4] = (w2.x >> 16) | (w2.y & 0xffff0000u);
      hd[5] = (w2.z >> 16) | (w2.w & 0xffff0000u);
      hd[6] = (w3.x >> 16) | (w3.y & 0xffff0000u);
      hd[7] = (w3.z >> 16) | (w3.w & 0xffff0000u);
    }
    __syncthreads();   // S1: hs ready

    // C: partial gates over this wave's K chunk
    floatx4 acc = {0.f, 0.f, 0.f, 0.f};
#pragma unroll
    for (int s8 = 0; s8 < 8; s8++) {
      short8 af = *(const short8*)(hs + nloc * 1032 + kt * 256 + s8 * 32 + q * 8);
      acc = __builtin_amdgcn_mfma_f32_16x16x32_bf16(af, bfr[s8], acc, 0, 0, 0);
    }
    if (kt) {
#pragma unroll
      for (int r = 0; r < 4; r++) red[kt - 1][nt][q * 4 + r][nloc] = acc[r];
    }
    __syncthreads();   // S2: red ready; all hs reads complete

    // D: epilogue (kt==0 waves): gates, direct publish, direct out stores.
    // kt!=0 waves fall straight through to the next hint barrier.
    if (kt == 0) {
      float gv[4];
#pragma unroll
      for (int r = 0; r < 4; r++)
        gv[r] = acc[r] + red[0][nt][q * 4 + r][nloc] + red[1][nt][q * 4 + r][nloc]
              + red[2][nt][q * 4 + r][nloc] + xv[r];
      unsigned* hw32 = hb32 + (size_t)((t + 1) & 1) * (B_ * H_);
      const int sb = q << 4;
#pragma unroll
      for (int r = 0; r < 4; r++) {
        float vi = __shfl(gv[r], sb + u);
        float vf = __shfl(gv[r], sb + 4 + u);
        float vg = __shfl(gv[r], sb + 8 + u);
        float vo = __shfl(gv[r], sb + 12 + u);
        float i_ = sigf(vi), f_ = sigf(vf), g_ = tanhf_fast(vg), o_ = sigf(vo);
        float cn = f_ * cst[r] + i_ * g_;
        cst[r] = cn;
        float hn = o_ * tanhf_fast(cn);
        if (tg == 0) {
          const int m = (q << 2) + r;
          out_hid[(size_t)(r0 + m) * (S_ * H_) + (size_t)t * H_ + j] = hn;  // plain store
          if (t < 511) {
            unsigned pv = (((unsigned)bf16_rne(hn)) << 16) | (unsigned)(t + 1);
            astore32(hw32 + (((size_t)(r0 + m)) << 10) + j, pv);  // tagged publish
          } else {
            out_h[((r0 + m) << 10) + j] = hn;
            out_c[((r0 + m) << 10) + j] = cn;
          }
        }
      }
      // hint store: fire right after this wave's publishes; ordering vs other
      // waves' publishes irrelevant (tags cover), so no waits of any kind.
      if (wv == 0 && ln == 0 && t < 511) astore32(arr_bg + cg, (unsigned)(t + 1));
    }
    // no S3/S4: next iteration's hint barrier + S1 provide all needed fences
  }
}

// ---------------- host ----------------
extern "C" void kernel_launch(void* const* d_in, const int* in_sizes, int n_in,
                              void* d_out, int out_size, void* d_ws, size_t ws_size,
                              hipStream_t stream) {
  const float* x  = (const float*)d_in[0];
  const float* h0 = (const float*)d_in[1];
  const float* c0 = (const float*)d_in[2];
  const float* Wi = (const float*)d_in[3];
  const float* bi = (const float*)d_in[4];
  const float* Wh = (const float*)d_in[5];
  const float* bh = (const float*)d_in[6];

  float* out_hid = (float*)d_out;
  float* out_h = out_hid + (size_t)B_ * S_ * H_;
  float* out_c = out_h + (size_t)B_ * H_;

  uint8_t* ws = (uint8_t*)d_ws;
  const size_t xg_fp32 = (size_t)S_ * B_ * G_ * 4;   // 512 MB
  const size_t xg_bf16 = (size_t)S_ * B_ * G_ * 2;   // 256 MB
  const size_t xbf_b = (size_t)B_ * S_ * D_ * 2;     // 64 MB
  const size_t w_b = (size_t)G_ * D_ * 2;            // 8 MB each
  const size_t hb_b = (size_t)2 * B_ * H_ * 4;       // 512 KB tagged h
  const size_t rest = xbf_b + 2 * w_b + (size_t)G_ * 4 + hb_b + 8192;
  int xg16 = (ws_size >= xg_fp32 + rest) ? 0 : 1;
  size_t xg_bytes = xg16 ? xg_bf16 : xg_fp32;

  size_t off = 0;
  void* xg = (void*)(ws + off);                      off += xg_bytes;
  unsigned short* xbf = (unsigned short*)(ws + off); off += xbf_b;
  unsigned short* wib = (unsigned short*)(ws + off); off += w_b;
  unsigned short* whb = (unsigned short*)(ws + off); off += w_b;
  float* bsum = (float*)(ws + off);                  off += (size_t)G_ * 4;
  unsigned* hb32 = (unsigned*)(ws + off);            off += hb_b;
  off = (off + 255) & ~(size_t)255;
  unsigned* arrp = (unsigned*)(ws + off);

  // arr -> 0 (t=0 hint passes); hb32 tags -> 0xFFFF (no stale match), h(0) tag 0
  hipMemsetAsync(arrp, 0, 4096, stream);
  hipMemsetAsync(hb32, 0xFF, hb_b, stream);
  f32_to_bf16_k<<<(B_ * S_ * D_ / 4 + 255) / 256, 256, 0, stream>>>(x, xbf, B_ * S_ * D_);
  f32_to_bf16_k<<<(G_ * D_ / 4 + 255) / 256, 256, 0, stream>>>(Wi, wib, G_ * D_);
  f32_to_bf16_k<<<(G_ * D_ / 4 + 255) / 256, 256, 0, stream>>>(Wh, whb, G_ * D_);
  bsum_k<<<G_ / 256, 256, 0, stream>>>(bi, bh, bsum);
  hinit_k<<<(B_ * H_ + 255) / 256, 256, 0, stream>>>(h0, hb32);

  gemm_xg<<<dim3((S_ * B_ / 128) * (G_ / 128)), 256, 0, stream>>>(xbf, wib, bsum, xg, xg16);

  void* args[] = { (void*)&xg, (void*)&xg16, (void*)&whb, (void*)&hb32, (void*)&c0,
                   (void*)&out_hid, (void*)&out_h, (void*)&out_c, (void*)&arrp };
  hipLaunchCooperativeKernel((void*)lstm_rec, dim3(NBLK), dim3(1024), args, 0, stream);
}

// Round 7
// 3195.924 us; speedup vs baseline: 1.0778x; 1.0683x over previous
//
#include <hip/hip_runtime.h>
#include <cstdint>
#include <cstddef>

#define B_ 64
#define S_ 512
#define D_ 1024
#define H_ 1024
#define G_ 4096       // 4*H
#define NBLK 256      // cooperative grid for recurrence

typedef short short8 __attribute__((ext_vector_type(8)));
typedef float floatx4 __attribute__((ext_vector_type(4)));

__device__ __forceinline__ unsigned short bf16_rne(float f) {
  union { float f; unsigned u; } v; v.f = f;
  return (unsigned short)((v.u + 0x7FFFu + ((v.u >> 16) & 1u)) >> 16);
}
__device__ __forceinline__ float sigf(float x) { return 1.0f / (1.0f + __expf(-x)); }
__device__ __forceinline__ float tanhf_fast(float x) {
  float e = __expf(2.0f * x);
  return 1.0f - 2.0f / (e + 1.0f);   // safe at +-inf (no NaN)
}

// agent-scope per-access coherent ops (sc0|sc1 cache-bypass, NO wbl2/inv tag walks)
__device__ __forceinline__ void astore64(void* p, uint64_t v) {
  __hip_atomic_store((unsigned long long*)p, (unsigned long long)v,
                     __ATOMIC_RELAXED, __HIP_MEMORY_SCOPE_AGENT);
}
__device__ __forceinline__ void astore32(unsigned* p, unsigned v) {
  __hip_atomic_store(p, v, __ATOMIC_RELAXED, __HIP_MEMORY_SCOPE_AGENT);
}
__device__ __forceinline__ unsigned aload32(const unsigned* p) {
  return __hip_atomic_load(p, __ATOMIC_RELAXED, __HIP_MEMORY_SCOPE_AGENT);
}
// two coherent 16B loads, one wait (L1/L2-bypass via sc0|sc1)
__device__ __forceinline__ void cload2x128(uint4* d0, uint4* d1, const void* p0, const void* p1) {
  asm volatile("global_load_dwordx4 %0, %2, off sc0 sc1\n\t"
               "global_load_dwordx4 %1, %3, off sc0 sc1\n\t"
               "s_waitcnt vmcnt(0)"
               : "=&v"(*d0), "=&v"(*d1)
               : "v"(p0), "v"(p1)
               : "memory");
}

// async global->LDS, 16B per lane (m97 ladder step; LDS dest linear in lane order)
__device__ __forceinline__ void gload_lds16(const unsigned short* g, unsigned short* l) {
  __builtin_amdgcn_global_load_lds(
      (const __attribute__((address_space(1))) unsigned int*)g,
      (__attribute__((address_space(3))) unsigned int*)l,
      16, 0, 0);
}

// ---------------- prep kernels ----------------
__global__ void f32_to_bf16_k(const float* __restrict__ s, unsigned short* __restrict__ d, int n) {
  int i = (blockIdx.x * 256 + threadIdx.x) * 4;
  if (i < n) {
    float4 v = *(const float4*)(s + i);
    ushort4 o;
    o.x = bf16_rne(v.x); o.y = bf16_rne(v.y); o.z = bf16_rne(v.z); o.w = bf16_rne(v.w);
    *(ushort4*)(d + i) = o;
  }
}

__global__ void bsum_k(const float* __restrict__ bi, const float* __restrict__ bh, float* __restrict__ o) {
  int i = blockIdx.x * 256 + threadIdx.x;
  if (i < G_) o[i] = bi[i] + bh[i];
}

__global__ void hinit_k(const float* __restrict__ h0, unsigned short* __restrict__ hb) {
  int i = blockIdx.x * 256 + threadIdx.x;   // 0..65535
  if (i < B_ * H_) hb[i] = bf16_rne(h0[i & (H_ - 1)]);
}

// ---------------- phase 1: xg = x @ Wi^T + (bi+bh) ----------------
// r0 structure upgraded per the measured ladder (m93->m97): global_load_lds
// width-16 staging (linear [128][64] LDS, no pad -- required for the direct
// LDS write path) + bijective XCD-aware blockIdx swizzle (nwg=8192, %8==0).
__global__ __launch_bounds__(256, 3) void gemm_xg(
    const unsigned short* __restrict__ xa,   // [32768][1024] bf16 (token-major: b*512+s)
    const unsigned short* __restrict__ wb,   // [4096][1024] bf16
    const float* __restrict__ bsum,          // [4096]
    void* __restrict__ xgv, int xg16)        // out: [512][64][4096]
{
  __shared__ unsigned short As[128 * 64];
  __shared__ unsigned short Bs[128 * 64];
  const int tid = threadIdx.x, ln = tid & 63, wv = tid >> 6;
  const int q = ln >> 4, lr = ln & 15;
  // XCD swizzle: consecutive bids (same A-panel) stay on one XCD's L2
  const int bid = ((blockIdx.x & 7) << 10) | (blockIdx.x >> 3);
  const int nt = bid & 31, mt = bid >> 5;
  const int m0 = mt << 7, n0 = nt << 7;
  const int wm = (wv & 1) << 6, wn = (wv >> 1) << 6;
  floatx4 acc[4][4] = {};

  for (int kk = 0; kk < 1024; kk += 64) {
    __syncthreads();   // prior ds_reads done before overwrite
#pragma unroll
    for (int i = 0; i < 4; i++) {
      int f = i * 256 + tid;
      int row = f >> 3, c8 = (f & 7) << 3;
      gload_lds16(xa + (size_t)(m0 + row) * 1024 + kk + c8, As + f * 8);
      gload_lds16(wb + (size_t)(n0 + row) * 1024 + kk + c8, Bs + f * 8);
    }
    __syncthreads();   // vmcnt(0) drain -> LDS tiles resident
#pragma unroll
    for (int ks = 0; ks < 2; ks++) {
      short8 af[4], bf[4];
#pragma unroll
      for (int mi = 0; mi < 4; mi++)
        af[mi] = *(const short8*)(As + (wm + mi * 16 + lr) * 64 + ks * 32 + q * 8);
#pragma unroll
      for (int ni = 0; ni < 4; ni++)
        bf[ni] = *(const short8*)(Bs + (wn + ni * 16 + lr) * 64 + ks * 32 + q * 8);
#pragma unroll
      for (int mi = 0; mi < 4; mi++)
#pragma unroll
        for (int ni = 0; ni < 4; ni++)
          acc[mi][ni] = __builtin_amdgcn_mfma_f32_16x16x32_bf16(af[mi], bf[ni], acc[mi][ni], 0, 0, 0);
    }
  }
  const int b = m0 >> 9, s0 = m0 & 511;
#pragma unroll
  for (int mi = 0; mi < 4; mi++) {
#pragma unroll
    for (int r = 0; r < 4; r++) {
      int mrow = wm + mi * 16 + q * 4 + r;
      size_t base = (size_t)(s0 + mrow) * (B_ * G_) + (size_t)b * G_;
#pragma unroll
      for (int ni = 0; ni < 4; ni++) {
        int n = n0 + wn + ni * 16 + lr;
        float v = acc[mi][ni][r] + bsum[n];
        if (xg16) ((unsigned short*)xgv)[base + n] = bf16_rne(v);
        else      ((float*)xgv)[base + n] = v;
      }
    }
  }
}

// ---------------- phase 2: persistent cooperative recurrence ----------------
// r0-proven (2619 us): 256 blocks = 4 batch-groups x 64 col-groups; per-bg
// flag-tree barrier (arrival slots + aggregator wave + replicated flags).
__global__ __launch_bounds__(1024, 1) void lstm_rec(
    const void* __restrict__ xgv, int xg16,  // [512][64][4096] (biases folded in)
    const unsigned short* __restrict__ wh,   // [4096][1024] bf16
    unsigned short* __restrict__ hb,         // [2][64][1024] bf16 (double buffer)
    const float* __restrict__ c0,            // [1024]
    float* __restrict__ out_hid,             // [64][512][1024]
    float* __restrict__ out_h,               // [64][1024]
    float* __restrict__ out_c,               // [64][1024]
    unsigned* __restrict__ sync)             // arr[4][64] @0 ; flag[4][8 reps][16] @+256
{
  __shared__ unsigned short hs[16 * 1032];   // h tile, padded rows (+8 elems)
  __shared__ float red[3][4][16][16];        // K-split partials [kt-1][nt][m][n]
  __shared__ unsigned short hout_bf[256];    // 16x16 h tile bf16 (publish)
  __shared__ float hout_f[256];              // 16x16 h tile fp32 (out_hid)

  const int tid = threadIdx.x, ln = tid & 63, wv = tid >> 6;
  const int nt = wv & 3, kt = wv >> 2;
  const int bid = blockIdx.x, bg = bid & 3, cg = bid >> 2;
  const int r0 = bg << 4, j0 = cg << 4;
  const int nloc = ln & 15, q = ln >> 4;
  const int tg = nloc >> 2, u = nloc & 3;
  const int j = j0 + (nt << 2) + u;
  const int gcol = tg * 1024 + j;

  unsigned* arr_bg = sync + (bg << 6);            // 64 dwords
  unsigned* flag_bg = sync + 256 + (bg << 7);     // 8 reps x 16 dwords

  short8 bfr[8];
#pragma unroll
  for (int s8 = 0; s8 < 8; s8++)
    bfr[s8] = *(const short8*)(wh + (size_t)gcol * 1024 + kt * 256 + s8 * 32 + q * 8);

  float cst[4];
#pragma unroll
  for (int r = 0; r < 4; r++) cst[r] = c0[j];

  for (int t = 0; t < 512; t++) {
    const unsigned short* hr = hb + (t & 1) * (B_ * H_);
    unsigned short* hw = hb + ((t + 1) & 1) * (B_ * H_);

    // A: xg prefetch (plain cached loads; independent of h)
    float xv[4] = {0.f, 0.f, 0.f, 0.f};
    if (kt == 0) {
      const size_t xbase = (size_t)t * (B_ * G_) + (size_t)r0 * G_ + gcol;
      if (xg16) {
#pragma unroll
        for (int r = 0; r < 4; r++) {
          unsigned short w = ((const unsigned short*)xgv)[xbase + (size_t)(q * 4 + r) * G_];
          union { unsigned uu; float ff; } cv; cv.uu = ((unsigned)w) << 16; xv[r] = cv.ff;
        }
      } else {
#pragma unroll
        for (int r = 0; r < 4; r++)
          xv[r] = ((const float*)xgv)[xbase + (size_t)(q * 4 + r) * G_];
      }
    }

    // B: stage h tile 16x1024 bf16 -> LDS via two 16B coherent loads per thread
    {
      int g0 = tid, g1 = tid + 1024;           // 2048 16B chunks
      const void* p0 = hr + ((r0 + (g0 >> 7)) << 10) + ((g0 & 127) << 3);
      const void* p1 = hr + ((r0 + (g1 >> 7)) << 10) + ((g1 & 127) << 3);
      uint4 a, b;
      cload2x128(&a, &b, p0, p1);
      *(uint4*)(hs + (g0 >> 7) * 1032 + ((g0 & 127) << 3)) = a;
      *(uint4*)(hs + (g1 >> 7) * 1032 + ((g1 & 127) << 3)) = b;
    }
    __syncthreads();   // S1: hs ready

    // C: partial gates over this wave's K chunk
    floatx4 acc = {0.f, 0.f, 0.f, 0.f};
#pragma unroll
    for (int s8 = 0; s8 < 8; s8++) {
      short8 af = *(const short8*)(hs + nloc * 1032 + kt * 256 + s8 * 32 + q * 8);
      acc = __builtin_amdgcn_mfma_f32_16x16x32_bf16(af, bfr[s8], acc, 0, 0, 0);
    }
    if (kt) {
#pragma unroll
      for (int r = 0; r < 4; r++) red[kt - 1][nt][q * 4 + r][nloc] = acc[r];
    }
    __syncthreads();   // S2: red ready

    // D: epilogue (kt==0 waves)
    if (kt == 0) {
      float gv[4];
#pragma unroll
      for (int r = 0; r < 4; r++)
        gv[r] = acc[r] + red[0][nt][q * 4 + r][nloc] + red[1][nt][q * 4 + r][nloc]
              + red[2][nt][q * 4 + r][nloc] + xv[r];
      const int sb = q << 4;
#pragma unroll
      for (int r = 0; r < 4; r++) {
        float vi = __shfl(gv[r], sb + u);
        float vf = __shfl(gv[r], sb + 4 + u);
        float vg = __shfl(gv[r], sb + 8 + u);
        float vo = __shfl(gv[r], sb + 12 + u);
        float i_ = sigf(vi), f_ = sigf(vf), g_ = tanhf_fast(vg), o_ = sigf(vo);
        float cn = f_ * cst[r] + i_ * g_;
        cst[r] = cn;
        float hn = o_ * tanhf_fast(cn);
        if (tg == 0) {
          int m = (q << 2) + r;
          hout_bf[(m << 4) + (nt << 2) + u] = bf16_rne(hn);
          hout_f [(m << 4) + (nt << 2) + u] = hn;
          if (t == 511) {
            int brow = r0 + m;
            out_h[(brow << 10) + j] = hn;
            out_c[(brow << 10) + j] = cn;
          }
        }
      }
    }
    __syncthreads();   // S3: hout ready

    if (wv == 0) {
      // E: publish h (64 lanes x 8B agent stores -> L3)
      int row = ln >> 2, c4 = (ln & 3) << 2;
      uint64_t hv = *(const uint64_t*)(hout_bf + (row << 4) + c4);
      astore64(hw + ((r0 + row) << 10) + j0 + c4, hv);
      __asm__ volatile("" ::: "memory");
      __builtin_amdgcn_s_waitcnt(0);           // h acked at coherence point
      __asm__ volatile("" ::: "memory");
      if (t < 511) {
        if (ln == 0) astore32(arr_bg + cg, (unsigned)(t + 1));  // arrival (no RMW)
        const unsigned tgt = (unsigned)(t + 1);
        if (cg == 0) {
          // aggregator: whole wave polls 64 arrival slots, min-reduce, publish flags
          for (;;) {
            unsigned v = aload32(arr_bg + ln);
#pragma unroll
            for (int d = 32; d >= 1; d >>= 1) {
              unsigned o = __shfl_xor(v, d);
              v = v < o ? v : o;
            }
            if (v >= tgt) break;
            __builtin_amdgcn_s_sleep(2);
          }
          if (ln < 8) astore32(flag_bg + (ln << 4), tgt);
        } else if (ln == 0) {
          // peer: poll one replica line (<=8 pollers per line)
          const unsigned* fl = flag_bg + ((cg & 7) << 4);
          while (aload32(fl) < tgt) __builtin_amdgcn_s_sleep(8);
        }
      }
    } else if (wv == 1) {
      // F: out_hid rows (plain cached stores; drain overlaps next staging)
      int row = ln >> 2, c4 = (ln & 3) << 2;
      float4 fv = *(const float4*)(hout_f + (row << 4) + c4);
      *(float4*)(out_hid + (size_t)(r0 + row) * (S_ * H_) + (size_t)t * H_ + j0 + c4) = fv;
    }
    __syncthreads();   // S4: bg's h published & visible; safe to read hb[(t+1)&1]
  }
}

// ---------------- host ----------------
extern "C" void kernel_launch(void* const* d_in, const int* in_sizes, int n_in,
                              void* d_out, int out_size, void* d_ws, size_t ws_size,
                              hipStream_t stream) {
  const float* x  = (const float*)d_in[0];
  const float* h0 = (const float*)d_in[1];
  const float* c0 = (const float*)d_in[2];
  const float* Wi = (const float*)d_in[3];
  const float* bi = (const float*)d_in[4];
  const float* Wh = (const float*)d_in[5];
  const float* bh = (const float*)d_in[6];

  float* out_hid = (float*)d_out;
  float* out_h = out_hid + (size_t)B_ * S_ * H_;
  float* out_c = out_h + (size_t)B_ * H_;

  uint8_t* ws = (uint8_t*)d_ws;
  const size_t xg_fp32 = (size_t)S_ * B_ * G_ * 4;   // 512 MB
  const size_t xg_bf16 = (size_t)S_ * B_ * G_ * 2;   // 256 MB
  const size_t xbf_b = (size_t)B_ * S_ * D_ * 2;     // 64 MB
  const size_t w_b = (size_t)G_ * D_ * 2;            // 8 MB each
  const size_t rest = xbf_b + 2 * w_b + (size_t)G_ * 4 + (size_t)2 * B_ * H_ * 2 + 8192;
  int xg16 = (ws_size >= xg_fp32 + rest) ? 0 : 1;
  size_t xg_bytes = xg16 ? xg_bf16 : xg_fp32;

  size_t off = 0;
  void* xg = (void*)(ws + off);                      off += xg_bytes;
  unsigned short* xbf = (unsigned short*)(ws + off); off += xbf_b;
  unsigned short* wib = (unsigned short*)(ws + off); off += w_b;
  unsigned short* whb = (unsigned short*)(ws + off); off += w_b;
  float* bsum = (float*)(ws + off);                  off += (size_t)G_ * 4;
  unsigned short* hb = (unsigned short*)(ws + off);  off += (size_t)2 * B_ * H_ * 2;
  off = (off + 255) & ~(size_t)255;
  unsigned* syncp = (unsigned*)(ws + off);

  hipMemsetAsync(syncp, 0, 4096, stream);
  f32_to_bf16_k<<<(B_ * S_ * D_ / 4 + 255) / 256, 256, 0, stream>>>(x, xbf, B_ * S_ * D_);
  f32_to_bf16_k<<<(G_ * D_ / 4 + 255) / 256, 256, 0, stream>>>(Wi, wib, G_ * D_);
  f32_to_bf16_k<<<(G_ * D_ / 4 + 255) / 256, 256, 0, stream>>>(Wh, whb, G_ * D_);
  bsum_k<<<G_ / 256, 256, 0, stream>>>(bi, bh, bsum);
  hinit_k<<<(B_ * H_ + 255) / 256, 256, 0, stream>>>(h0, hb);

  gemm_xg<<<dim3((S_ * B_ / 128) * (G_ / 128)), 256, 0, stream>>>(xbf, wib, bsum, xg, xg16);

  void* args[] = { (void*)&xg, (void*)&xg16, (void*)&whb, (void*)&hb, (void*)&c0,
                   (void*)&out_hid, (void*)&out_h, (void*)&out_c, (void*)&syncp };
  hipLaunchCooperativeKernel((void*)lstm_rec, dim3(NBLK), dim3(1024), args, 0, stream);
}